// Round 7
// baseline (271.044 us; speedup 1.0000x reference)
//
#include <hip/hip_runtime.h>

#define B_ 8
#define T_ 256
#define U_ 101
#define V_ 512
#define UM1 (U_ - 1)
#define NS 164    // DP stages = U_ + T_/4 - 1 = 101 + 63
#define NSG 42    // groups processed (42*4 = 168 >= NS)
#define NSPG 45   // groups allocated (prefetch reads up to group 41+3 = 44)
#define NSP (NSPG * 4)
#define NEG -1e30f
#define LOG2E 1.4426950408889634f
#define LN2 0.6931471805599453f

typedef float floatx4 __attribute__((ext_vector_type(4)));

// logaddexp in log2 domain: returns log2(2^a + 2^b)
__device__ __forceinline__ float lae2(float a, float b) {
  float m = fmaxf(a, b);
  float d = fminf(a, b) - m;
  return m + __builtin_log2f(1.0f + __builtin_exp2f(d));
}

// Two rows of V=512 logits per wave (4 KB contiguous), wave index linear in
// acts memory order. Max-free logsumexp in log2 domain. Writes blank/emit
// log2-probs SKEW-INDEXED for the DP kernel:
//   blank[t,u] -> blankS[b][u + (t+1)/4][(t+1)/4][(t+1)%4]   (t < T-1)
//   emit [t,u] -> emitS [b][u + 1 + t/4][ t/4 ][ t%4 ]
// Also writes bp2[b] = log2 P(blank | tlen-1, ulen) for the final loss term.
__global__ __launch_bounds__(256) void lse_kernel(
    const float* __restrict__ acts, const int* __restrict__ labels,
    const int* __restrict__ act_lens, const int* __restrict__ label_lens,
    float* __restrict__ blankS, float* __restrict__ emitS,
    float* __restrict__ bp2) {
  const int wv = blockIdx.x * 4 + (threadIdx.x >> 6);
  const int lane = threadIdx.x & 63;
  const int r0 = wv * 2;        // row = (b*T + t)*U + u
  const int r1 = r0 + 1;
  const floatx4* p0 = (const floatx4*)(acts + (size_t)r0 * V_);
  const floatx4* p1 = (const floatx4*)(acts + (size_t)r1 * V_);
  floatx4 a0 = p0[lane];
  floatx4 a1 = p0[lane + 64];
  floatx4 c0 = p1[lane];
  floatx4 c1 = p1[lane + 64];
  float s0 = __builtin_exp2f(a0.x * LOG2E) + __builtin_exp2f(a0.y * LOG2E) +
             __builtin_exp2f(a0.z * LOG2E) + __builtin_exp2f(a0.w * LOG2E) +
             __builtin_exp2f(a1.x * LOG2E) + __builtin_exp2f(a1.y * LOG2E) +
             __builtin_exp2f(a1.z * LOG2E) + __builtin_exp2f(a1.w * LOG2E);
  float s1 = __builtin_exp2f(c0.x * LOG2E) + __builtin_exp2f(c0.y * LOG2E) +
             __builtin_exp2f(c0.z * LOG2E) + __builtin_exp2f(c0.w * LOG2E) +
             __builtin_exp2f(c1.x * LOG2E) + __builtin_exp2f(c1.y * LOG2E) +
             __builtin_exp2f(c1.z * LOG2E) + __builtin_exp2f(c1.w * LOG2E);
#pragma unroll
  for (int s = 32; s >= 1; s >>= 1) {
    s0 += __shfl_xor(s0, s);
    s1 += __shfl_xor(s1, s);
  }
  const float d0 = __builtin_log2f(s0);
  const float d1 = __builtin_log2f(s1);

#define EMIT_ROW(r, v0, v1, denom2)                                           \
  {                                                                           \
    const int u = (r) % U_;                                                   \
    const int bt = (r) / U_;                                                  \
    const int t = bt % T_;                                                    \
    const int b = bt / T_;                                                    \
    float emitv = 0.0f;                                                       \
    if (u < UM1) {                                                            \
      int e = labels[b * UM1 + u]; /* in [1, V) */                            \
      floatx4 sel = (e < 256) ? v0 : v1;                                      \
      int k = e & 3;                                                          \
      float cand =                                                            \
          (k == 0) ? sel.x : (k == 1) ? sel.y : (k == 2) ? sel.z : sel.w;     \
      emitv = __shfl(cand, (e & 255) >> 2);                                   \
    }                                                                         \
    if (lane == 0) {                                                          \
      const float blank2 = v0.x * LOG2E - (denom2);                           \
      if (t < T_ - 1) {                                                       \
        const int lb = (t + 1) >> 2;                                          \
        blankS[(((size_t)b * NSP + (u + lb)) * 64 + lb) * 4 + ((t + 1) & 3)] =\
            blank2;                                                           \
      }                                                                       \
      if (u < UM1) {                                                          \
        const int le = t >> 2;                                                \
        emitS[(((size_t)b * NSP + (u + 1 + le)) * 64 + le) * 4 + (t & 3)] =   \
            emitv * LOG2E - (denom2);                                         \
      }                                                                       \
      if (t == act_lens[b] - 1 && u == label_lens[b]) bp2[b] = blank2;        \
    }                                                                         \
  }

  EMIT_ROW(r0, a0, a1, d0)
  EMIT_ROW(r1, c0, c1, d1)
#undef EMIT_ROW
}

// One wave per example; lane l owns rows t in [4l, 4l+4). Stage s computes
// column u = s - lane (skewed wavefront). Per stage: two coalesced dwordx4
// loads (12-stage-deep prefetch via 3 rotating named buffer groups) + one
// shfl_up + 4 chained lae2. All DP math in log2 domain.
__global__ __launch_bounds__(64) void dp_kernel(
    const float* __restrict__ blankS, const float* __restrict__ emitS,
    const float* __restrict__ bp2, const int* __restrict__ act_lens,
    const int* __restrict__ label_lens, float* __restrict__ out) {
  const int b = blockIdx.x;
  const int lane = threadIdx.x;
  const int tlen = act_lens[b];
  const int ulen = label_lens[b];
  const int ltar = (tlen - 1) >> 2;
  const int rtar = (tlen - 1) & 3;
  const floatx4* pB = (const floatx4*)(blankS + (size_t)b * NSP * 256) + lane;
  const floatx4* pE = (const floatx4*)(emitS + (size_t)b * NSP * 256) + lane;
  floatx4 bA[4], eA[4], bB[4], eB[4], bC[4], eC[4];
#pragma unroll
  for (int k = 0; k < 4; ++k) {
    bA[k] = pB[k * 64];        eA[k] = pE[k * 64];
    bB[k] = pB[256 + k * 64];  eB[k] = pE[256 + k * 64];
    bC[k] = pB[512 + k * 64];  eC[k] = pE[512 + k * 64];
  }
  float x0 = NEG, x1 = NEG, x2 = NEG, x3 = NEG, res = NEG;

#define GSTEP(bX, eX, GOFF)                                                  \
  _Pragma("unroll") for (int k = 0; k < 4; ++k) {                            \
    const int s = 4 * (g + (GOFF)) + k;                                      \
    const floatx4 Bv = bX[k];                                                \
    const floatx4 Ev = eX[k];                                                \
    bX[k] = pB[((GOFF) + 3) * 256 + k * 64]; /* refill group g+GOFF+3 */     \
    eX[k] = pE[((GOFF) + 3) * 256 + k * 64];                                 \
    const float carry = __shfl_up(x3, 1);                                    \
    const int u = s - lane;                                                  \
    if (u >= 0 && u < U_) {                                                  \
      const bool u0 = (u == 0);                                              \
      const float h0 = u0 ? NEG : x0 + Ev.x;                                 \
      const float h1 = u0 ? NEG : x1 + Ev.y;                                 \
      const float h2 = u0 ? NEG : x2 + Ev.z;                                 \
      const float h3 = u0 ? NEG : x3 + Ev.w;                                 \
      const float vv = (lane == 0) ? NEG : carry + Bv.x;                     \
      float a0 = lae2(vv, h0);                                               \
      if (lane == 0 && u0) a0 = 0.0f; /* alpha[0,0] = 0 */                   \
      const float a1 = lae2(a0 + Bv.y, h1);                                  \
      const float a2 = lae2(a1 + Bv.z, h2);                                  \
      const float a3 = lae2(a2 + Bv.w, h3);                                  \
      if (u == ulen && lane == ltar)                                         \
        res = (rtar == 0) ? a0 : (rtar == 1) ? a1 : (rtar == 2) ? a2 : a3;   \
      x0 = a0; x1 = a1; x2 = a2; x3 = a3;                                    \
    }                                                                        \
  }

  for (int g = 0; g < NSG; g += 3) {  // 14 iterations, groups 0..41
    GSTEP(bA, eA, 0)
    GSTEP(bB, eB, 1)
    GSTEP(bC, eC, 2)
    pB += 3 * 256;
    pE += 3 * 256;
  }
#undef GSTEP
  if (lane == ltar) out[b] = -((res + bp2[b]) * LN2);
}

extern "C" void kernel_launch(void* const* d_in, const int* in_sizes, int n_in,
                              void* d_out, int out_size, void* d_ws, size_t ws_size,
                              hipStream_t stream) {
  const float* acts = (const float*)d_in[0];
  const int* labels = (const int*)d_in[1];
  const int* act_lens = (const int*)d_in[2];
  const int* label_lens = (const int*)d_in[3];
  float* out = (float*)d_out;
  float* blankS = (float*)d_ws;                      // B*NSP*256 floats
  float* emitS = blankS + (size_t)B_ * NSP * 256;    // B*NSP*256 floats
  float* bp2 = emitS + (size_t)B_ * NSP * 256;       // B floats
  float* dummy_out = bp2 + 64;                       // scratch for timing runs
  const int nwaves2 = B_ * T_ * U_ / 2;              // 103,424 (div by 4)
  lse_kernel<<<nwaves2 / 4, 256, 0, stream>>>(acts, labels, act_lens,
                                              label_lens, blankS, emitS, bp2);
  // MEASUREMENT ROUND: 3 dummy dp replicas (identical work, output to ws
  // scratch) amplify dp's duration x3 in dur_us; final replica is the real one.
  dp_kernel<<<B_, 64, 0, stream>>>(blankS, emitS, bp2, act_lens, label_lens,
                                   dummy_out);
  dp_kernel<<<B_, 64, 0, stream>>>(blankS, emitS, bp2, act_lens, label_lens,
                                   dummy_out);
  dp_kernel<<<B_, 64, 0, stream>>>(blankS, emitS, bp2, act_lens, label_lens,
                                   dummy_out);
  dp_kernel<<<B_, 64, 0, stream>>>(blankS, emitS, bp2, act_lens, label_lens,
                                   out);
}

// Round 8
// 140.414 us; speedup vs baseline: 1.9303x; 1.9303x over previous
//
#include <hip/hip_runtime.h>

#define B_ 8
#define T_ 256
#define U_ 101
#define V_ 512
#define UM1 (U_ - 1)
#define NS 164    // DP stages = U_ + T_/4 - 1 = 101 + 63
#define NSG 42    // groups processed (42*4 = 168 >= NS)
#define NSPG 45   // groups allocated (prefetch reads up to group 41+3 = 44)
#define NSP (NSPG * 4)
#define NEG -1e30f
#define LOG2E 1.4426950408889634f
#define LN2 0.6931471805599453f

typedef float floatx4 __attribute__((ext_vector_type(4)));

// logaddexp in log2 domain: returns log2(2^a + 2^b)
__device__ __forceinline__ float lae2(float a, float b) {
  float m = fmaxf(a, b);
  float d = fminf(a, b) - m;
  return m + __builtin_log2f(1.0f + __builtin_exp2f(d));
}

// lane n <- lane n-1 at VALU latency (DPP wave_shr:1). Lane 0 gets 0
// (old operand); callers mask lane 0 explicitly.
__device__ __forceinline__ float wave_shr1(float x) {
  int r = __builtin_amdgcn_update_dpp(0, __float_as_int(x), 0x138, 0xF, 0xF,
                                      false);
  return __int_as_float(r);
}

// Two rows of V=512 logits per wave (4 KB contiguous), wave index linear in
// acts memory order. Max-free logsumexp in log2 domain. Writes blank/emit
// log2-probs SKEW-INDEXED for the DP kernel:
//   blank[t,u] -> blankS[b][u + (t+1)/4][(t+1)/4][(t+1)%4]   (t < T-1)
//   emit [t,u] -> emitS [b][u + 1 + t/4][ t/4 ][ t%4 ]
// Also writes bp2[b] = log2 P(blank | tlen-1, ulen) for the final loss term.
__global__ __launch_bounds__(256) void lse_kernel(
    const float* __restrict__ acts, const int* __restrict__ labels,
    const int* __restrict__ act_lens, const int* __restrict__ label_lens,
    float* __restrict__ blankS, float* __restrict__ emitS,
    float* __restrict__ bp2) {
  const int wv = blockIdx.x * 4 + (threadIdx.x >> 6);
  const int lane = threadIdx.x & 63;
  const int r0 = wv * 2;        // row = (b*T + t)*U + u
  const int r1 = r0 + 1;
  const floatx4* p0 = (const floatx4*)(acts + (size_t)r0 * V_);
  const floatx4* p1 = (const floatx4*)(acts + (size_t)r1 * V_);
  floatx4 a0 = p0[lane];
  floatx4 a1 = p0[lane + 64];
  floatx4 c0 = p1[lane];
  floatx4 c1 = p1[lane + 64];
  float s0 = __builtin_exp2f(a0.x * LOG2E) + __builtin_exp2f(a0.y * LOG2E) +
             __builtin_exp2f(a0.z * LOG2E) + __builtin_exp2f(a0.w * LOG2E) +
             __builtin_exp2f(a1.x * LOG2E) + __builtin_exp2f(a1.y * LOG2E) +
             __builtin_exp2f(a1.z * LOG2E) + __builtin_exp2f(a1.w * LOG2E);
  float s1 = __builtin_exp2f(c0.x * LOG2E) + __builtin_exp2f(c0.y * LOG2E) +
             __builtin_exp2f(c0.z * LOG2E) + __builtin_exp2f(c0.w * LOG2E) +
             __builtin_exp2f(c1.x * LOG2E) + __builtin_exp2f(c1.y * LOG2E) +
             __builtin_exp2f(c1.z * LOG2E) + __builtin_exp2f(c1.w * LOG2E);
#pragma unroll
  for (int s = 32; s >= 1; s >>= 1) {
    s0 += __shfl_xor(s0, s);
    s1 += __shfl_xor(s1, s);
  }
  const float d0 = __builtin_log2f(s0);
  const float d1 = __builtin_log2f(s1);

#define EMIT_ROW(r, v0, v1, denom2)                                           \
  {                                                                           \
    const int u = (r) % U_;                                                   \
    const int bt = (r) / U_;                                                  \
    const int t = bt % T_;                                                    \
    const int b = bt / T_;                                                    \
    float emitv = 0.0f;                                                       \
    if (u < UM1) {                                                            \
      int e = labels[b * UM1 + u]; /* in [1, V) */                            \
      floatx4 sel = (e < 256) ? v0 : v1;                                      \
      int k = e & 3;                                                          \
      float cand =                                                            \
          (k == 0) ? sel.x : (k == 1) ? sel.y : (k == 2) ? sel.z : sel.w;     \
      emitv = __shfl(cand, (e & 255) >> 2);                                   \
    }                                                                         \
    if (lane == 0) {                                                          \
      const float blank2 = v0.x * LOG2E - (denom2);                           \
      if (t < T_ - 1) {                                                       \
        const int lb = (t + 1) >> 2;                                          \
        blankS[(((size_t)b * NSP + (u + lb)) * 64 + lb) * 4 + ((t + 1) & 3)] =\
            blank2;                                                           \
      }                                                                       \
      if (u < UM1) {                                                          \
        const int le = t >> 2;                                                \
        emitS[(((size_t)b * NSP + (u + 1 + le)) * 64 + le) * 4 + (t & 3)] =   \
            emitv * LOG2E - (denom2);                                         \
      }                                                                       \
      if (t == act_lens[b] - 1 && u == label_lens[b]) bp2[b] = blank2;        \
    }                                                                         \
  }

  EMIT_ROW(r0, a0, a1, d0)
  EMIT_ROW(r1, c0, c1, d1)
#undef EMIT_ROW
}

// One wave per example; lane l owns rows t in [4l, 4l+4). Stage s computes
// column u = s - lane (skewed wavefront). Critical-path engineering:
//  - carry via DPP wave_shr:1 (VALU latency, not LDS);
//  - carry-decoupled column update: a_t' computed with carry=-inf (depends
//    only on previous stage), then x_t = lae2(a_t', carry + prefixB_t), so
//    the cross-stage chain is dpp -> add -> one lae2.
// 12-stage-deep register prefetch via 3 rotating named buffer groups.
__global__ __launch_bounds__(64) void dp_kernel(
    const float* __restrict__ blankS, const float* __restrict__ emitS,
    const float* __restrict__ bp2, const int* __restrict__ act_lens,
    const int* __restrict__ label_lens, float* __restrict__ out) {
  const int b = blockIdx.x;
  const int lane = threadIdx.x;
  const int tlen = act_lens[b];
  const int ulen = label_lens[b];
  const int ltar = (tlen - 1) >> 2;
  const int rtar = (tlen - 1) & 3;
  const floatx4* pB = (const floatx4*)(blankS + (size_t)b * NSP * 256) + lane;
  const floatx4* pE = (const floatx4*)(emitS + (size_t)b * NSP * 256) + lane;
  floatx4 bA[4], eA[4], bB[4], eB[4], bC[4], eC[4];
#pragma unroll
  for (int k = 0; k < 4; ++k) {
    bA[k] = pB[k * 64];        eA[k] = pE[k * 64];
    bB[k] = pB[256 + k * 64];  eB[k] = pE[256 + k * 64];
    bC[k] = pB[512 + k * 64];  eC[k] = pE[512 + k * 64];
  }
  float x0 = NEG, x1 = NEG, x2 = NEG, x3 = NEG, res = NEG;

#define GSTEP(bX, eX, GOFF)                                                  \
  _Pragma("unroll") for (int k = 0; k < 4; ++k) {                            \
    const int s = 4 * (g + (GOFF)) + k;                                      \
    const floatx4 Bv = bX[k];                                                \
    const floatx4 Ev = eX[k];                                                \
    bX[k] = pB[((GOFF) + 3) * 256 + k * 64]; /* refill group g+GOFF+3 */     \
    eX[k] = pE[((GOFF) + 3) * 256 + k * 64];                                 \
    const float carry = wave_shr1(x3);                                       \
    const int u = s - lane;                                                  \
    if (u >= 0 && u < U_) {                                                  \
      const bool u0 = (u == 0);                                              \
      const float ct = (lane == 0) ? NEG : carry;                            \
      const float P0 = Bv.x;                                                 \
      const float P1 = P0 + Bv.y;                                            \
      const float P2 = P1 + Bv.z;                                            \
      const float P3 = P2 + Bv.w;                                            \
      const float h0 = u0 ? NEG : x0 + Ev.x;                                 \
      const float h1 = u0 ? NEG : x1 + Ev.y;                                 \
      const float h2 = u0 ? NEG : x2 + Ev.z;                                 \
      const float h3 = u0 ? NEG : x3 + Ev.w;                                 \
      const float a0p = h0;                                                  \
      float nx0 = lae2(a0p, ct + P0);                                        \
      const float a1p = lae2(a0p + Bv.y, h1);                                \
      float nx1 = lae2(a1p, ct + P1);                                        \
      const float a2p = lae2(a1p + Bv.z, h2);                                \
      float nx2 = lae2(a2p, ct + P2);                                        \
      const float a3p = lae2(a2p + Bv.w, h3);                                \
      float nx3 = lae2(a3p, ct + P3);                                        \
      if (lane == 0 && u0) { /* alpha[*,0] = pure blank chain from 0 */      \
        nx0 = 0.0f;                                                          \
        nx1 = Bv.y;                                                          \
        nx2 = Bv.y + Bv.z;                                                   \
        nx3 = Bv.y + Bv.z + Bv.w;                                            \
      }                                                                      \
      if (u == ulen && lane == ltar)                                         \
        res = (rtar == 0) ? nx0 : (rtar == 1) ? nx1 : (rtar == 2) ? nx2      \
                                                                  : nx3;    \
      x0 = nx0; x1 = nx1; x2 = nx2; x3 = nx3;                                \
    }                                                                        \
  }

  for (int g = 0; g < NSG; g += 3) {  // 14 iterations, groups 0..41
    GSTEP(bA, eA, 0)
    GSTEP(bB, eB, 1)
    GSTEP(bC, eC, 2)
    pB += 3 * 256;
    pE += 3 * 256;
  }
#undef GSTEP
  if (lane == ltar) out[b] = -((res + bp2[b]) * LN2);
}

extern "C" void kernel_launch(void* const* d_in, const int* in_sizes, int n_in,
                              void* d_out, int out_size, void* d_ws, size_t ws_size,
                              hipStream_t stream) {
  const float* acts = (const float*)d_in[0];
  const int* labels = (const int*)d_in[1];
  const int* act_lens = (const int*)d_in[2];
  const int* label_lens = (const int*)d_in[3];
  float* out = (float*)d_out;
  float* blankS = (float*)d_ws;                      // B*NSP*256 floats
  float* emitS = blankS + (size_t)B_ * NSP * 256;    // B*NSP*256 floats
  float* bp2 = emitS + (size_t)B_ * NSP * 256;       // B floats
  const int nwaves2 = B_ * T_ * U_ / 2;              // 103,424 (div by 4)
  lse_kernel<<<nwaves2 / 4, 256, 0, stream>>>(acts, labels, act_lens,
                                              label_lens, blankS, emitS, bp2);
  dp_kernel<<<B_, 64, 0, stream>>>(blankS, emitS, bp2, act_lens, label_lens,
                                   out);
}

// Round 9
// 138.755 us; speedup vs baseline: 1.9534x; 1.0120x over previous
//
#include <hip/hip_runtime.h>

#define B_ 8
#define T_ 256
#define U_ 101
#define V_ 512
#define UM1 (U_ - 1)
#define DSTR 128    // floats per diagonal row (u-index stride)
#define DALLOC 392  // diagonals allocated (loop reads d up to 384)
#define NEG -1e30f
#define LOG2E 1.4426950408889634f
#define LN2 0.6931471805599453f

typedef float floatx4 __attribute__((ext_vector_type(4)));
typedef float floatx2 __attribute__((ext_vector_type(2)));

// logaddexp in log2 domain: returns log2(2^a + 2^b)
__device__ __forceinline__ float lae2(float a, float b) {
  float m = fmaxf(a, b);
  float d = fminf(a, b) - m;
  return m + __builtin_log2f(1.0f + __builtin_exp2f(d));
}

// lane n <- lane n-1 (DPP wave_shr:1, VALU latency). Lane 0 <- NEG.
__device__ __forceinline__ float wave_shr1_neg(float x) {
  int r = __builtin_amdgcn_update_dpp(__float_as_int(NEG), __float_as_int(x),
                                      0x138, 0xF, 0xF, false);
  return __int_as_float(r);
}

// Two rows of V=512 logits per wave (4 KB contiguous), wave index linear in
// acts memory order. Max-free logsumexp in log2 domain. Stores blank/emit
// log2-probs DIAGONAL-MAJOR for the DP kernel (consumed at stage d):
//   blank[t,u] -> blankD[b][t+u+1][u]      (vertical input of alpha[t+1,u])
//   t==0 phantom: blankD[b][u][u] = NEG    (vertical input of alpha[0,u])
//   emit [t,u] -> emitD [b][t+u+1][u+1]    (horizontal input of alpha[t,u+1])
// Also writes bp2[b] = log2 P(blank | tlen-1, ulen).
__global__ __launch_bounds__(256) void lse_kernel(
    const float* __restrict__ acts, const int* __restrict__ labels,
    const int* __restrict__ act_lens, const int* __restrict__ label_lens,
    float* __restrict__ blankD, float* __restrict__ emitD,
    float* __restrict__ bp2) {
  const int wv = blockIdx.x * 4 + (threadIdx.x >> 6);
  const int lane = threadIdx.x & 63;
  const int r0 = wv * 2;  // row = (b*T + t)*U + u
  const int r1 = r0 + 1;
  const floatx4* p0 = (const floatx4*)(acts + (size_t)r0 * V_);
  const floatx4* p1 = (const floatx4*)(acts + (size_t)r1 * V_);
  floatx4 a0 = p0[lane];
  floatx4 a1 = p0[lane + 64];
  floatx4 c0 = p1[lane];
  floatx4 c1 = p1[lane + 64];
  float s0 = __builtin_exp2f(a0.x * LOG2E) + __builtin_exp2f(a0.y * LOG2E) +
             __builtin_exp2f(a0.z * LOG2E) + __builtin_exp2f(a0.w * LOG2E) +
             __builtin_exp2f(a1.x * LOG2E) + __builtin_exp2f(a1.y * LOG2E) +
             __builtin_exp2f(a1.z * LOG2E) + __builtin_exp2f(a1.w * LOG2E);
  float s1 = __builtin_exp2f(c0.x * LOG2E) + __builtin_exp2f(c0.y * LOG2E) +
             __builtin_exp2f(c0.z * LOG2E) + __builtin_exp2f(c0.w * LOG2E) +
             __builtin_exp2f(c1.x * LOG2E) + __builtin_exp2f(c1.y * LOG2E) +
             __builtin_exp2f(c1.z * LOG2E) + __builtin_exp2f(c1.w * LOG2E);
#pragma unroll
  for (int s = 32; s >= 1; s >>= 1) {
    s0 += __shfl_xor(s0, s);
    s1 += __shfl_xor(s1, s);
  }
  const float d0 = __builtin_log2f(s0);
  const float d1 = __builtin_log2f(s1);

#define EMIT_ROW(r, v0, v1, denom2)                                           \
  {                                                                           \
    const int u = (r) % U_;                                                   \
    const int bt = (r) / U_;                                                  \
    const int t = bt % T_;                                                    \
    const int b = bt / T_;                                                    \
    float emitv = 0.0f;                                                       \
    if (u < UM1) {                                                            \
      int e = labels[b * UM1 + u]; /* in [1, V) */                            \
      floatx4 sel = (e < 256) ? v0 : v1;                                      \
      int k = e & 3;                                                          \
      float cand =                                                            \
          (k == 0) ? sel.x : (k == 1) ? sel.y : (k == 2) ? sel.z : sel.w;     \
      emitv = __shfl(cand, (e & 255) >> 2);                                   \
    }                                                                         \
    if (lane == 0) {                                                          \
      const float blank2 = v0.x * LOG2E - (denom2);                           \
      blankD[((size_t)b * DALLOC + (t + u + 1)) * DSTR + u] = blank2;         \
      if (t == 0) blankD[((size_t)b * DALLOC + u) * DSTR + u] = NEG;          \
      if (u < UM1)                                                            \
        emitD[((size_t)b * DALLOC + (t + u + 1)) * DSTR + (u + 1)] =          \
            emitv * LOG2E - (denom2);                                         \
      if (t == act_lens[b] - 1 && u == label_lens[b]) bp2[b] = blank2;        \
    }                                                                         \
  }

  EMIT_ROW(r0, a0, a1, d0)
  EMIT_ROW(r1, c0, c1, d1)
#undef EMIT_ROW
}

// One wave per example. Anti-diagonal wavefront; lane l owns columns u=2l
// (even) and u=2l+1 (odd). alpha(d)[u] = lae2(alpha(d-1)[u] + blank,
// alpha(d-1)[u-1] + emit). Odd's left neighbor = same lane's even register;
// even's left neighbor = one DPP wave_shr of odd. Per-stage serial chain:
// dpp + add + ONE lae2. Two coalesced dwordx2 loads/stage, 24-stage-deep
// register prefetch (3 rotating groups of 8; all indices compile-time).
__global__ __launch_bounds__(64, 1) void dp_kernel(
    const float* __restrict__ blankD, const float* __restrict__ emitD,
    const float* __restrict__ bp2, const int* __restrict__ act_lens,
    const int* __restrict__ label_lens, float* __restrict__ out) {
  const int b = blockIdx.x;
  const int lane = threadIdx.x;
  const int tl1 = act_lens[b] - 1;
  const int ulen = label_lens[b];
  const int dtar = tl1 + ulen;
  const int uE = 2 * lane;
  const int uO = 2 * lane + 1;
  const bool capE = ((ulen & 1) == 0) && (lane == (ulen >> 1));
  const bool capO = ((ulen & 1) == 1) && (lane == (ulen >> 1));
  const floatx2* baseB =
      (const floatx2*)(blankD + (size_t)b * DALLOC * DSTR) + lane;
  const floatx2* baseE =
      (const floatx2*)(emitD + (size_t)b * DALLOC * DSTR) + lane;
  // Group gi holds stages s = gi*8 + k (k<8); stage s is diagonal d = s+1.
  floatx2 bA[8], eA[8], bB[8], eB[8], bC[8], eC[8];
#pragma unroll
  for (int k = 0; k < 8; ++k) {
    bA[k] = baseB[(k + 1) * 64];   eA[k] = baseE[(k + 1) * 64];
    bB[k] = baseB[(k + 9) * 64];   eB[k] = baseE[(k + 9) * 64];
    bC[k] = baseB[(k + 17) * 64];  eC[k] = baseE[(k + 17) * 64];
  }
  float xE = (lane == 0) ? 0.0f : NEG;  // alpha[0,0] at diagonal 0
  float xO = NEG;
  float res = NEG;

#define GSTEP(bX, eX, GOFF)                                                   \
  _Pragma("unroll") for (int k = 0; k < 8; ++k) {                             \
    const int d = base_s + (GOFF) * 8 + k + 1;                                \
    const floatx2 Bv = bX[k];                                                 \
    const floatx2 Ev = eX[k];                                                 \
    bX[k] = baseB[(size_t)(base_s + ((GOFF) + 3) * 8 + k + 1) * 64];          \
    eX[k] = baseE[(size_t)(base_s + ((GOFF) + 3) * 8 + k + 1) * 64];          \
    const float xm1E = wave_shr1_neg(xO); /* col uE-1, prev diagonal */       \
    const float vtE = (uE >= d) ? NEG : xE + Bv.x;  /* t==0: no vertical */   \
    const float htE = (lane == 0) ? NEG : xm1E + Ev.x; /* u==0: no horiz */   \
    const float vtO = (uO >= d) ? NEG : xO + Bv.y;                            \
    const float htO = xE + Ev.y; /* col uO-1 = same lane's even */            \
    const float nxE = lae2(vtE, htE);                                         \
    const float nxO = lae2(vtO, htO);                                         \
    const bool vE = (uE <= d) && (d - uE <= tl1) && (uE <= UM1);              \
    const bool vO = (uO <= d) && (d - uO <= tl1) && (uO <= UM1);              \
    xE = vE ? nxE : xE;                                                       \
    xO = vO ? nxO : xO;                                                       \
    if (d == dtar) res = capE ? xE : (capO ? xO : res);                       \
  }

  for (int i = 0; i < 15; ++i) {  // 15 * 24 = 360 stages >= dtar_max 355
    const int base_s = i * 24;
    GSTEP(bA, eA, 0)
    GSTEP(bB, eB, 1)
    GSTEP(bC, eC, 2)
  }
#undef GSTEP
  if (capE || capO) out[b] = -((res + bp2[b]) * LN2);
}

extern "C" void kernel_launch(void* const* d_in, const int* in_sizes, int n_in,
                              void* d_out, int out_size, void* d_ws, size_t ws_size,
                              hipStream_t stream) {
  const float* acts = (const float*)d_in[0];
  const int* labels = (const int*)d_in[1];
  const int* act_lens = (const int*)d_in[2];
  const int* label_lens = (const int*)d_in[3];
  float* out = (float*)d_out;
  float* blankD = (float*)d_ws;                         // B*DALLOC*DSTR floats
  float* emitD = blankD + (size_t)B_ * DALLOC * DSTR;   // B*DALLOC*DSTR floats
  float* bp2 = emitD + (size_t)B_ * DALLOC * DSTR;      // B floats
  const int nwaves2 = B_ * T_ * U_ / 2;                 // 103,424 (div by 4)
  lse_kernel<<<nwaves2 / 4, 256, 0, stream>>>(acts, labels, act_lens,
                                              label_lens, blankD, emitD, bp2);
  dp_kernel<<<B_, 64, 0, stream>>>(blankD, emitD, bp2, act_lens, label_lens,
                                   out);
}

// Round 10
// 133.448 us; speedup vs baseline: 2.0311x; 1.0398x over previous
//
#include <hip/hip_runtime.h>

#define B_ 8
#define T_ 256
#define U_ 101
#define V_ 512
#define UM1 (U_ - 1)
#define DSTR 128    // floats per diagonal row (u-index stride)
#define DALLOC 488  // diagonals allocated (prefetch reads up to 448)
#define CH 32       // DP stages per LDS chunk
#define NCH 12      // chunks computed (12*32 = 384 >= 355 needed)
#define NEG -1e30f
#define LOG2E 1.4426950408889634f
#define LN2 0.6931471805599453f

typedef float floatx4 __attribute__((ext_vector_type(4)));
typedef float floatx2 __attribute__((ext_vector_type(2)));

// logaddexp in log2 domain: returns log2(2^a + 2^b)
__device__ __forceinline__ float lae2(float a, float b) {
  float m = fmaxf(a, b);
  float d = fminf(a, b) - m;
  return m + __builtin_log2f(1.0f + __builtin_exp2f(d));
}

// lane n <- lane n-1 (DPP wave_shr:1, VALU latency). Lane 0 <- NEG.
__device__ __forceinline__ float wave_shr1_neg(float x) {
  int r = __builtin_amdgcn_update_dpp(__float_as_int(NEG), __float_as_int(x),
                                      0x138, 0xF, 0xF, false);
  return __int_as_float(r);
}

// Two rows of V=512 logits per wave (4 KB contiguous), wave index linear in
// acts memory order. Max-free logsumexp in log2 domain. Stores blank/emit
// log2-probs DIAGONAL-MAJOR for the DP kernel (consumed at stage d):
//   blank[t,u] -> blankD[b][t+u+1][u]      (vertical input of alpha[t+1,u])
//   t==0 phantom: blankD[b][u][u] = NEG    (vertical input of alpha[0,u])
//   emit [t,u] -> emitD [b][t+u+1][u+1]    (horizontal input of alpha[t,u+1])
// Also writes bp2[b] = log2 P(blank | tlen-1, ulen).
__global__ __launch_bounds__(256) void lse_kernel(
    const float* __restrict__ acts, const int* __restrict__ labels,
    const int* __restrict__ act_lens, const int* __restrict__ label_lens,
    float* __restrict__ blankD, float* __restrict__ emitD,
    float* __restrict__ bp2) {
  const int wv = blockIdx.x * 4 + (threadIdx.x >> 6);
  const int lane = threadIdx.x & 63;
  const int r0 = wv * 2;  // row = (b*T + t)*U + u
  const int r1 = r0 + 1;
  const floatx4* p0 = (const floatx4*)(acts + (size_t)r0 * V_);
  const floatx4* p1 = (const floatx4*)(acts + (size_t)r1 * V_);
  floatx4 a0 = p0[lane];
  floatx4 a1 = p0[lane + 64];
  floatx4 c0 = p1[lane];
  floatx4 c1 = p1[lane + 64];
  float s0 = __builtin_exp2f(a0.x * LOG2E) + __builtin_exp2f(a0.y * LOG2E) +
             __builtin_exp2f(a0.z * LOG2E) + __builtin_exp2f(a0.w * LOG2E) +
             __builtin_exp2f(a1.x * LOG2E) + __builtin_exp2f(a1.y * LOG2E) +
             __builtin_exp2f(a1.z * LOG2E) + __builtin_exp2f(a1.w * LOG2E);
  float s1 = __builtin_exp2f(c0.x * LOG2E) + __builtin_exp2f(c0.y * LOG2E) +
             __builtin_exp2f(c0.z * LOG2E) + __builtin_exp2f(c0.w * LOG2E) +
             __builtin_exp2f(c1.x * LOG2E) + __builtin_exp2f(c1.y * LOG2E) +
             __builtin_exp2f(c1.z * LOG2E) + __builtin_exp2f(c1.w * LOG2E);
#pragma unroll
  for (int s = 32; s >= 1; s >>= 1) {
    s0 += __shfl_xor(s0, s);
    s1 += __shfl_xor(s1, s);
  }
  const float d0 = __builtin_log2f(s0);
  const float d1 = __builtin_log2f(s1);

#define EMIT_ROW(r, v0, v1, denom2)                                           \
  {                                                                           \
    const int u = (r) % U_;                                                   \
    const int bt = (r) / U_;                                                  \
    const int t = bt % T_;                                                    \
    const int b = bt / T_;                                                    \
    float emitv = 0.0f;                                                       \
    if (u < UM1) {                                                            \
      int e = labels[b * UM1 + u]; /* in [1, V) */                            \
      floatx4 sel = (e < 256) ? v0 : v1;                                      \
      int k = e & 3;                                                          \
      float cand =                                                            \
          (k == 0) ? sel.x : (k == 1) ? sel.y : (k == 2) ? sel.z : sel.w;     \
      emitv = __shfl(cand, (e & 255) >> 2);                                   \
    }                                                                         \
    if (lane == 0) {                                                          \
      const float blank2 = v0.x * LOG2E - (denom2);                           \
      blankD[((size_t)b * DALLOC + (t + u + 1)) * DSTR + u] = blank2;         \
      if (t == 0) blankD[((size_t)b * DALLOC + u) * DSTR + u] = NEG;          \
      if (u < UM1)                                                            \
        emitD[((size_t)b * DALLOC + (t + u + 1)) * DSTR + (u + 1)] =          \
            emitv * LOG2E - (denom2);                                         \
      if (t == act_lens[b] - 1 && u == label_lens[b]) bp2[b] = blank2;        \
    }                                                                         \
  }

  EMIT_ROW(r0, a0, a1, d0)
  EMIT_ROW(r1, c0, c1, d1)
#undef EMIT_ROW
}

// One wave per example. Anti-diagonal wavefront; lane l owns columns u=2l,
// 2l+1. Per-stage serial chain: DPP wave_shr + add + one lae2. ZERO VMEM in
// the stage loop: chunks of 32 diagonals are staged global->regs->LDS,
// double-buffered; stage loop reads LDS only (ds_read_b64, 4-deep register
// prefetch). VMEM waits happen once per chunk, overlapped with compute.
__global__ __launch_bounds__(64, 1) void dp_kernel(
    const float* __restrict__ blankD, const float* __restrict__ emitD,
    const float* __restrict__ bp2, const int* __restrict__ act_lens,
    const int* __restrict__ label_lens, float* __restrict__ out) {
  __shared__ float lds[2][2][CH][DSTR];  // [buf][blank/emit][slot][u] = 64 KB
  const int b = blockIdx.x;
  const int lane = threadIdx.x;
  const int tl1 = act_lens[b] - 1;
  const int ulen = label_lens[b];
  const int dtar = tl1 + ulen;
  const int uE = 2 * lane;
  const int uO = 2 * lane + 1;
  const bool capE = ((ulen & 1) == 0) && (lane == (ulen >> 1));
  const bool capO = ((ulen & 1) == 1) && (lane == (ulen >> 1));
  const floatx4* g4B = (const floatx4*)(blankD + (size_t)b * DALLOC * DSTR);
  const floatx4* g4E = (const floatx4*)(emitD + (size_t)b * DALLOC * DSTR);

  floatx4 rB[16], rE[16];
  // Prologue: chunk 0 (diagonals 1..32) -> regs -> buf 0.
#pragma unroll
  for (int j = 0; j < 16; ++j) {
    rB[j] = g4B[32 + j * 64 + lane];  // dlo(0)=1 -> 32 in x4 units
    rE[j] = g4E[32 + j * 64 + lane];
  }
  {
    floatx4* lB4 = (floatx4*)&lds[0][0][0][0];
    floatx4* lE4 = (floatx4*)&lds[0][1][0][0];
#pragma unroll
    for (int j = 0; j < 16; ++j) {
      lB4[j * 64 + lane] = rB[j];
      lE4[j * 64 + lane] = rE[j];
    }
  }
  float xE = (lane == 0) ? 0.0f : NEG;  // alpha[0,0] at diagonal 0
  float xO = NEG;
  float res = NEG;

  for (int c = 0; c < NCH; ++c) {
    const int buf = c & 1;
    // Issue chunk c+1 global loads (32 independent dwordx4; consumed only at
    // the write block after compute -> no vmcnt waits inside the stage loop).
    const int nb = ((c + 1) * CH + 1) * 32;  // x4 units
#pragma unroll
    for (int j = 0; j < 16; ++j) {
      rB[j] = g4B[(size_t)nb + j * 64 + lane];
      rE[j] = g4E[(size_t)nb + j * 64 + lane];
    }
    // Compute chunk c from LDS.
    const floatx2* lB2 = (const floatx2*)&lds[buf][0][0][0];
    const floatx2* lE2 = (const floatx2*)&lds[buf][1][0][0];
    floatx2 pB[4], pE[4];
#pragma unroll
    for (int k = 0; k < 4; ++k) {
      pB[k] = lB2[k * 64 + lane];
      pE[k] = lE2[k * 64 + lane];
    }
    const int dbase = c * CH + 1;
#pragma unroll
    for (int k = 0; k < CH; ++k) {
      const int d = dbase + k;
      const floatx2 Bv = pB[k & 3];
      const floatx2 Ev = pE[k & 3];
      if (k + 4 < CH) {
        pB[k & 3] = lB2[(k + 4) * 64 + lane];
        pE[k & 3] = lE2[(k + 4) * 64 + lane];
      }
      const float xm1E = wave_shr1_neg(xO);  // col uE-1, prev diagonal
      // Boundary handling: t==0 vertical comes from the phantom NEG written
      // by lse; u==0 horizontal comes from the DPP old-operand NEG. Garbage
      // cells only feed lanes whose validity mask is false.
      const float vtE = xE + Bv.x;
      const float htE = xm1E + Ev.x;
      const float vtO = xO + Bv.y;
      const float htO = xE + Ev.y;  // col uO-1 = same lane's even column
      const float nxE = lae2(vtE, htE);
      const float nxO = lae2(vtO, htO);
      const bool vE = (d >= uE) && (d - uE <= tl1) && (uE <= UM1);
      const bool vO = (d >= uO) && (d - uO <= tl1) && (uO <= UM1);
      xE = vE ? nxE : xE;
      xO = vO ? nxO : xO;
      if (d == dtar) res = capE ? xE : (capO ? xO : res);
    }
    // Write staged chunk c+1 into the other buffer (in-order DS pipe makes
    // it visible to next iteration's reads; vmcnt waits land here).
    floatx4* wB4 = (floatx4*)&lds[buf ^ 1][0][0][0];
    floatx4* wE4 = (floatx4*)&lds[buf ^ 1][1][0][0];
#pragma unroll
    for (int j = 0; j < 16; ++j) {
      wB4[j * 64 + lane] = rB[j];
      wE4[j * 64 + lane] = rE[j];
    }
  }
  if (capE || capO) out[b] = -((res + bp2[b]) * LN2);
}

extern "C" void kernel_launch(void* const* d_in, const int* in_sizes, int n_in,
                              void* d_out, int out_size, void* d_ws, size_t ws_size,
                              hipStream_t stream) {
  const float* acts = (const float*)d_in[0];
  const int* labels = (const int*)d_in[1];
  const int* act_lens = (const int*)d_in[2];
  const int* label_lens = (const int*)d_in[3];
  float* out = (float*)d_out;
  float* blankD = (float*)d_ws;                         // B*DALLOC*DSTR floats
  float* emitD = blankD + (size_t)B_ * DALLOC * DSTR;   // B*DALLOC*DSTR floats
  float* bp2 = emitD + (size_t)B_ * DALLOC * DSTR;      // B floats
  const int nwaves2 = B_ * T_ * U_ / 2;                 // 103,424 (div by 4)
  lse_kernel<<<nwaves2 / 4, 256, 0, stream>>>(acts, labels, act_lens,
                                              label_lens, blankD, emitD, bp2);
  dp_kernel<<<B_, 64, 0, stream>>>(blankD, emitD, bp2, act_lens, label_lens,
                                   out);
}